// Round 2
// baseline (555.394 us; speedup 1.0000x reference)
//
#include <hip/hip_runtime.h>
#include <hip/hip_bf16.h>
#include <cstdint>
#include <cstddef>

typedef __bf16 bf16x8 __attribute__((ext_vector_type(8)));
typedef float floatx4 __attribute__((ext_vector_type(4)));

#define MFMA(a, b, c) __builtin_amdgcn_mfma_f32_16x16x32_bf16((a), (b), (c), 0, 0, 0)
#define WAITVM(N) asm volatile("s_waitcnt vmcnt(" #N ")" ::: "memory")
#define WAITLGKM0() asm volatile("s_waitcnt lgkmcnt(0)" ::: "memory")
#define BARRIER() do { asm volatile("" ::: "memory"); __builtin_amdgcn_s_barrier(); asm volatile("" ::: "memory"); } while (0)
#define SCHEDBAR() __builtin_amdgcn_sched_barrier(0)

__device__ __forceinline__ unsigned short f2bf(float f) {
  unsigned u = __builtin_bit_cast(unsigned, f);
  u += 0x7fffu + ((u >> 16) & 1u);
  return (unsigned short)(u >> 16);
}
__device__ __forceinline__ float bf2f(unsigned short h) {
  unsigned u = ((unsigned)h) << 16;
  return __builtin_bit_cast(float, u);
}
__device__ __forceinline__ float fast_exp2(float x) {
#if __has_builtin(__builtin_amdgcn_exp2f)
  return __builtin_amdgcn_exp2f(x);
#else
  return exp2f(x);
#endif
}

// async 16B global -> LDS DMA. LDS dest = wave-uniform base + lane*16.
__device__ __forceinline__ void gl2lds16(const unsigned short* g, unsigned short* l) {
  __builtin_amdgcn_global_load_lds(
      (const __attribute__((address_space(1))) unsigned int*)g,
      (__attribute__((address_space(3))) unsigned int*)l, 16, 0, 0);
}

// ---------------- fp32 -> bf16 convert (x) ----------------
__global__ void convert_f32_bf16(const float* __restrict__ src,
                                 unsigned short* __restrict__ dst, int n4) {
  int i = blockIdx.x * 256 + threadIdx.x;
  if (i >= n4) return;
  float4 f = ((const float4*)src)[i];
  ushort4 o;
  o.x = f2bf(f.x); o.y = f2bf(f.y); o.z = f2bf(f.z); o.w = f2bf(f.w);
  ((ushort4*)dst)[i] = o;
}

// ---------------- fp32 (K x N) -> bf16 transposed (N x K), 64x64 tiles ----------------
__global__ void transpose_f32_bf16(const float* __restrict__ src,
                                   unsigned short* __restrict__ dst, int K, int N) {
  __shared__ float tile[64 * 65];
  int tn = blockIdx.x * 64, tk = blockIdx.y * 64;
  int r = threadIdx.x >> 4;          // 0..15
  int c4 = (threadIdx.x & 15) * 4;   // 0,4,..,60
#pragma unroll
  for (int i = 0; i < 4; i++) {
    float4 f = *(const float4*)&src[(size_t)(tk + r + 16 * i) * N + tn + c4];
    float* tr = &tile[(r + 16 * i) * 65 + c4];
    tr[0] = f.x; tr[1] = f.y; tr[2] = f.z; tr[3] = f.w;
  }
  __syncthreads();
#pragma unroll
  for (int i = 0; i < 4; i++) {
    ushort4 o;
    o.x = f2bf(tile[(c4 + 0) * 65 + r + 16 * i]);
    o.y = f2bf(tile[(c4 + 1) * 65 + r + 16 * i]);
    o.z = f2bf(tile[(c4 + 2) * 65 + r + 16 * i]);
    o.w = f2bf(tile[(c4 + 3) * 65 + r + 16 * i]);
    *(ushort4*)&dst[(size_t)(tn + r + 16 * i) * K + tk + c4] = o;
  }
}

// ---------------- phased-pipeline bf16 GEMM: C = A(MxK) * Bt(NxK)^T ----------------
// BM=256, BN=NI*64 (NI=3 -> 192, NI=2 -> 128), BK=64, 512 threads (8 waves 2x4).
// Per-wave output 128 x NI*16 = acc[8][NI]. 4 phases per K-tile, fine interleave:
//   P1: read A-mh0 (both kk, 8x b128) + B-kk0 (NI)         | MFMA (mh0,kk0)
//   P2: read B-kk1 (NI) + A-mh1-kk0 (4) | stage A-c0,A-c2  | MFMA (mh0,kk1)
//   P3: read A-mh1-kk1 (4)              | stage B-c0..NI-1 | MFMA (mh1,kk0)
//   P4:                                 | stage A-c1,A-c3  | MFMA (mh1,kk1)
// Each phase: {reads; stages; barrier; lgkmcnt(0); setprio1; MFMA; setprio0; barrier}.
// Hazard proof: phase-p reads drain at p's own mid lgkmcnt(0); stages of a region
// are issued only in phases AFTER the last phase reading it (A-c0/c2: P1<P2;
// B: P2<P3; A-c1/c3: P3<P4). Staged tile T+2 lands in buf T&1 regions no phase
// of tile T re-reads. Single counted vmcnt(4+NI) at P4 (never 0 in steady state):
// leaves T+2's 4+NI loads in flight, forces T+1 landed before its P1 reads.
template <int NI, bool F32OUT>
__global__ __launch_bounds__(512, 2) void gemm_pipe(
    const unsigned short* __restrict__ A,
    const unsigned short* __restrict__ Bt,
    void* __restrict__ C, int M, int N, int K) {
  constexpr int BN = NI * 64;
  __shared__ alignas(16) unsigned short Al[2][256 * 64];
  __shared__ alignas(16) unsigned short Bl[2][BN * 64];
  const int tid = threadIdx.x;
  const int w = tid >> 6, L = tid & 63;
  const int lr = L & 15, lg = L >> 4, lr7 = lr & 7;
  // XCD-aware swizzle (grid = 256, %8==0): each XCD owns one bm-stripe -> shares A panel
  const int nbx = N / BN;
  const int sw = (blockIdx.x & 7) * ((int)gridDim.x >> 3) + (blockIdx.x >> 3);
  const int bn = (sw % nbx) * BN;
  const int bm = (sw / nbx) * 256;
  const int wm128 = (w >> 2) * 128;
  const int wn = (w & 3) * (NI * 16);
  const int NT = K >> 6;

  // staging map: thread -> (row = tid>>3 within 64-row chunk, colgroup = tid&7)
  // LDS dest = chunk base + tid*16B; source colgroup XOR-swizzled by row&7.
  const int srow = tid >> 3, scg = tid & 7;
  const unsigned short* Ag = &A[(size_t)(bm + srow) * K + ((scg ^ (srow & 7)) * 8)];
  const unsigned short* Bg = &Bt[(size_t)(bn + srow) * K + ((scg ^ (srow & 7)) * 8)];
  unsigned short* AlT = &Al[0][0] + tid * 8;
  unsigned short* BlT = &Bl[0][0] + tid * 8;

  // prologue: stage K-tiles 0 and 1 (A chunks c=0..3 of 64 rows; B chunks c=0..NI-1)
#pragma unroll
  for (int t = 0; t < 2; ++t) {
#pragma unroll
    for (int c = 0; c < 4; ++c)
      gl2lds16(Ag + (size_t)(c * 64) * K + t * 64, AlT + t * (256 * 64) + c * 4096);
#pragma unroll
    for (int c = 0; c < NI; ++c)
      gl2lds16(Bg + (size_t)(c * 64) * K + t * 64, BlT + t * (BN * 64) + c * 4096);
  }

  floatx4 acc[8][NI] = {};

  if constexpr (NI == 3) WAITVM(7); else WAITVM(6);  // tile0 landed, tile1 in flight
  BARRIER();

  for (int T = 0; T < NT; ++T) {
    const int b = T & 1;
    const unsigned short* Ab = &Al[b][0];
    const unsigned short* Bb = &Bl[b][0];
    const bool st = (T + 2) < NT;
    const size_t kofs = (size_t)(T + 2) * 64;
    unsigned short* Ad = AlT + b * (256 * 64);
    unsigned short* Bd = BlT + b * (BN * 64);
    bf16x8 a0[4][2], a1[4][2], bq[2][NI];

    // ---------- P1 ----------
#pragma unroll
    for (int mi = 0; mi < 4; ++mi) {
      a0[mi][0] = *(const bf16x8*)&Ab[(wm128 + mi * 16 + lr) * 64 + ((lg ^ lr7) * 8)];
      a0[mi][1] = *(const bf16x8*)&Ab[(wm128 + mi * 16 + lr) * 64 + (((4 + lg) ^ lr7) * 8)];
    }
#pragma unroll
    for (int ni = 0; ni < NI; ++ni)
      bq[0][ni] = *(const bf16x8*)&Bb[(wn + ni * 16 + lr) * 64 + ((lg ^ lr7) * 8)];
    BARRIER(); WAITLGKM0(); SCHEDBAR();
    __builtin_amdgcn_s_setprio(1);
#pragma unroll
    for (int mi = 0; mi < 4; ++mi)
#pragma unroll
      for (int ni = 0; ni < NI; ++ni)
        acc[mi][ni] = MFMA(a0[mi][0], bq[0][ni], acc[mi][ni]);
    __builtin_amdgcn_s_setprio(0);
    BARRIER();

    // ---------- P2 ----------
#pragma unroll
    for (int ni = 0; ni < NI; ++ni)
      bq[1][ni] = *(const bf16x8*)&Bb[(wn + ni * 16 + lr) * 64 + (((4 + lg) ^ lr7) * 8)];
#pragma unroll
    for (int mi = 0; mi < 4; ++mi)
      a1[mi][0] = *(const bf16x8*)&Ab[(wm128 + 64 + mi * 16 + lr) * 64 + ((lg ^ lr7) * 8)];
    if (st) {  // A rows 0-63 / 128-191: last read in P1
      gl2lds16(Ag + kofs, Ad);
      gl2lds16(Ag + (size_t)128 * K + kofs, Ad + 2 * 4096);
    }
    BARRIER(); WAITLGKM0(); SCHEDBAR();
    __builtin_amdgcn_s_setprio(1);
#pragma unroll
    for (int mi = 0; mi < 4; ++mi)
#pragma unroll
      for (int ni = 0; ni < NI; ++ni)
        acc[mi][ni] = MFMA(a0[mi][1], bq[1][ni], acc[mi][ni]);
    __builtin_amdgcn_s_setprio(0);
    BARRIER();

    // ---------- P3 ----------
#pragma unroll
    for (int mi = 0; mi < 4; ++mi)
      a1[mi][1] = *(const bf16x8*)&Ab[(wm128 + 64 + mi * 16 + lr) * 64 + (((4 + lg) ^ lr7) * 8)];
    if (st) {  // B rows: last read in P2
#pragma unroll
      for (int c = 0; c < NI; ++c)
        gl2lds16(Bg + (size_t)(c * 64) * K + kofs, Bd + c * 4096);
    }
    BARRIER(); WAITLGKM0(); SCHEDBAR();
    __builtin_amdgcn_s_setprio(1);
#pragma unroll
    for (int mi = 0; mi < 4; ++mi)
#pragma unroll
      for (int ni = 0; ni < NI; ++ni)
        acc[4 + mi][ni] = MFMA(a1[mi][0], bq[0][ni], acc[4 + mi][ni]);
    __builtin_amdgcn_s_setprio(0);
    BARRIER();

    // ---------- P4 ----------
    if (st) {  // A rows 64-127 / 192-255: last read in P3
      gl2lds16(Ag + (size_t)64 * K + kofs, Ad + 4096);
      gl2lds16(Ag + (size_t)192 * K + kofs, Ad + 3 * 4096);
    }
    BARRIER(); WAITLGKM0(); SCHEDBAR();
    __builtin_amdgcn_s_setprio(1);
#pragma unroll
    for (int mi = 0; mi < 4; ++mi)
#pragma unroll
      for (int ni = 0; ni < NI; ++ni)
        acc[4 + mi][ni] = MFMA(a1[mi][1], bq[1][ni], acc[4 + mi][ni]);
    __builtin_amdgcn_s_setprio(0);
    if constexpr (NI == 3) { if (st) { WAITVM(7); } else { WAITVM(0); } }
    else                   { if (st) { WAITVM(6); } else { WAITVM(0); } }
    BARRIER();
  }

#pragma unroll
  for (int mi = 0; mi < 8; ++mi) {
#pragma unroll
    for (int ni = 0; ni < NI; ++ni) {
#pragma unroll
      for (int r = 0; r < 4; ++r) {
        size_t row = bm + wm128 + mi * 16 + lg * 4 + r;
        size_t col = bn + wn + ni * 16 + lr;
        float v = acc[mi][ni][r];
        if constexpr (F32OUT) ((float*)C)[row * N + col] = v;
        else ((unsigned short*)C)[row * N + col] = f2bf(v);
      }
    }
  }
}

// ---------------- RoPE in place on bf16 rows, vectorized x4 ----------------
__global__ void rope_kernel(unsigned short* __restrict__ X, const float* __restrict__ cs,
                            int H, int rowStride, int colOff, float scale) {
  int idx = blockIdx.x * 256 + threadIdx.x;
  int dg = idx & 15;            // 4-wide d group: d = dg*4..dg*4+3
  int h = (idx >> 4) % H;
  int s = idx / (16 * H);
  size_t base = (size_t)s * rowStride + colOff + (size_t)h * 128 + dg * 4;
  ushort4 xa = *(const ushort4*)&X[base];
  ushort4 xb = *(const ushort4*)&X[base + 64];
  float4 c = *(const float4*)&cs[s * 64 + dg * 4];
  float4 sn = *(const float4*)&cs[2048 * 64 + s * 64 + dg * 4];
  ushort4 oa, ob;
  {
    float x1 = bf2f(xa.x), x2 = bf2f(xb.x);
    oa.x = f2bf((x1 * c.x + x2 * sn.x) * scale);
    ob.x = f2bf((x2 * c.x - x1 * sn.x) * scale);
  }
  {
    float x1 = bf2f(xa.y), x2 = bf2f(xb.y);
    oa.y = f2bf((x1 * c.y + x2 * sn.y) * scale);
    ob.y = f2bf((x2 * c.y - x1 * sn.y) * scale);
  }
  {
    float x1 = bf2f(xa.z), x2 = bf2f(xb.z);
    oa.z = f2bf((x1 * c.z + x2 * sn.z) * scale);
    ob.z = f2bf((x2 * c.z - x1 * sn.z) * scale);
  }
  {
    float x1 = bf2f(xa.w), x2 = bf2f(xb.w);
    oa.w = f2bf((x1 * c.w + x2 * sn.w) * scale);
    ob.w = f2bf((x2 * c.w - x1 * sn.w) * scale);
  }
  *(ushort4*)&X[base] = oa;
  *(ushort4*)&X[base + 64] = ob;
}

// ---------------- V (cols 5120.. of QKV, stride 6144) -> Vt (8,128,2048) ----------------
__global__ void v_transpose(const unsigned short* __restrict__ QKV,
                            unsigned short* __restrict__ Vt) {
  __shared__ unsigned short tile[32][33];
  int h = blockIdx.z;
  int s0 = blockIdx.x * 32, d0 = blockIdx.y * 32;
  int c = threadIdx.x & 31, r0 = threadIdx.x >> 5;
#pragma unroll
  for (int i = 0; i < 32; i += 8)
    tile[r0 + i][c] = QKV[(size_t)(s0 + r0 + i) * 6144 + 5120 + h * 128 + d0 + c];
  __syncthreads();
#pragma unroll
  for (int i = 0; i < 32; i += 8)
    Vt[(size_t)(h * 128 + d0 + r0 + i) * 2048 + s0 + c] = tile[c][r0 + i];
}

// ---------------- causal flash attention (v2) ----------------
// Block = 2 heads (same KV group) x 64 q-rows; 4 waves: wave w -> head
// hq = hk*4 + hp*2 + (w&1), q-rows [qb*64 + (w>>1)*32, +32) (2 row-tiles).
// K/V tile (64 positions) staged once per block via global_load_lds with
// source-side XOR colgroup swizzle (conflict-free ds_read_b128, zero staging
// VALU). 2x MFMA per staged byte vs v1. Fixed-max exp2 softmax (r3-validated).
__global__ __launch_bounds__(256) void flash_kernel(
    const unsigned short* __restrict__ QKV,  // (2048, 6144) roped; Q pre-scaled
    const unsigned short* __restrict__ Vt,   // (8, 128, 2048)
    unsigned short* __restrict__ O) {        // (2048, 4096)
  constexpr int PSTR = 72;
  __shared__ alignas(16) unsigned short Klds[64 * 128];   // 16 KB, swizzled cg16
  __shared__ alignas(16) unsigned short Vlds[128 * 64];   // 16 KB, swizzled cg8
  __shared__ alignas(16) unsigned short Plds[4 * 32 * PSTR];  // 18 KB wave-private
  const int tid = threadIdx.x, w = tid >> 6, L = tid & 63;
  const int lr = L & 15, lg = L >> 4;
  const int bid = blockIdx.x;
  const int hk = bid & 7;
  const int hp = (bid >> 3) & 1;
  const int qb = 31 - (bid >> 4);          // heavy blocks dispatch first
  const int hq = hk * 4 + hp * 2 + (w & 1);
  const int qr0 = qb * 64 + (w >> 1) * 32; // wave's 32 q-rows
  const unsigned short* Kg = QKV + 4096;

  // K staging (per thread, 4 issues/tile): row=flat>>4, lcg=flat&15,
  // source cg = lcg ^ (row&15)  -> LDS[row][lcg] holds logical cg lcg^(row&15)
  const int k_row = tid >> 4, k_lcg = tid & 15;
  const unsigned short* KgT = &Kg[(size_t)k_row * 6144 + hk * 128 + ((k_lcg ^ (k_row & 15)) * 8)];
  unsigned short* KlT = &Klds[k_row * 128 + k_lcg * 8];
  // V staging: row=flat>>3 (dh), lcg=flat&7, source cg = lcg ^ (row&7)
  const int v_row = tid >> 3, v_lcg = tid & 7;
  const unsigned short* VgT = &Vt[(size_t)(hk * 128 + v_row) * 2048 + ((v_lcg ^ (v_row & 7)) * 8)];
  unsigned short* VlT = &Vlds[v_row * 64 + v_lcg * 8];

  bf16x8 qf[2][4];
#pragma unroll
  for (int mi = 0; mi < 2; mi++)
#pragma unroll
    for (int c = 0; c < 4; c++)
      qf[mi][c] = *(const bf16x8*)&QKV[(size_t)(qr0 + mi * 16 + lr) * 6144 + hq * 128 + c * 32 + lg * 8];

  floatx4 oacc[2][8] = {};
  float l_lane[2][4] = {};
  unsigned short* pw = &Plds[w * 32 * PSTR];

  for (int t = 0; t <= qb; t++) {
    const int kv0 = t * 64;
    __syncthreads();  // previous tile's K/V reads done before restaging
#pragma unroll
    for (int i = 0; i < 4; i++) {
      gl2lds16(KgT + (size_t)(kv0 + i * 16) * 6144, KlT + i * 16 * 128);
      gl2lds16(VgT + kv0 + (size_t)(i * 32) * 2048, VlT + i * 32 * 64);
    }
    __syncthreads();

#pragma unroll
    for (int nt = 0; nt < 4; nt++) {
      bf16x8 kf[4];
#pragma unroll
      for (int c = 0; c < 4; c++)
        kf[c] = *(const bf16x8*)&Klds[(nt * 16 + lr) * 128 + (((c * 4 + lg) ^ lr) * 8)];
      floatx4 sc[2];
#pragma unroll
      for (int mi = 0; mi < 2; mi++) {
        floatx4 a = {};
#pragma unroll
        for (int c = 0; c < 4; c++) a = MFMA(qf[mi][c], kf[c], a);
        sc[mi] = a;
      }
      if (t == qb) {  // diagonal tile: causal mask
#pragma unroll
        for (int mi = 0; mi < 2; mi++)
#pragma unroll
          for (int r = 0; r < 4; r++)
            if (kv0 + nt * 16 + lr > qr0 + mi * 16 + lg * 4 + r) sc[mi][r] = -3e38f;
      }
#pragma unroll
      for (int mi = 0; mi < 2; mi++)
#pragma unroll
        for (int r = 0; r < 4; r++) {
          float p = fast_exp2(sc[mi][r]);
          l_lane[mi][r] += p;
          pw[(mi * 16 + lg * 4 + r) * PSTR + nt * 16 + lr] = f2bf(p);
        }
    }

    // P (wave-private) -> A-fragments; lgkmcnt orders ds_write->ds_read
    bf16x8 pf[2][2];
#pragma unroll
    for (int mi = 0; mi < 2; mi++)
#pragma unroll
      for (int c = 0; c < 2; c++)
        pf[mi][c] = *(const bf16x8*)&pw[(mi * 16 + lr) * PSTR + c * 32 + lg * 8];

#pragma unroll
    for (int n = 0; n < 8; n++) {
#pragma unroll
      for (int c = 0; c < 2; c++) {
        bf16x8 vf = *(const bf16x8*)&Vlds[(n * 16 + lr) * 64 + (((c * 4 + lg) ^ (lr & 7)) * 8)];
#pragma unroll
        for (int mi = 0; mi < 2; mi++) oacc[mi][n] = MFMA(pf[mi][c], vf, oacc[mi][n]);
      }
    }
  }

  // row-sum across the 16 lr lanes (masks 1..8 stay within lr group)
  float linv[2][4];
#pragma unroll
  for (int mi = 0; mi < 2; mi++)
#pragma unroll
    for (int r = 0; r < 4; r++) {
      float l = l_lane[mi][r];
      l += __shfl_xor(l, 1);
      l += __shfl_xor(l, 2);
      l += __shfl_xor(l, 4);
      l += __shfl_xor(l, 8);
      linv[mi][r] = 1.0f / l;
    }

#pragma unroll
  for (int mi = 0; mi < 2; mi++)
#pragma unroll
    for (int n = 0; n < 8; n++)
#pragma unroll
      for (int r = 0; r < 4; r++) {
        size_t row = qr0 + mi * 16 + lg * 4 + r;
        size_t col = (size_t)hq * 128 + n * 16 + lr;
        O[row * 4096 + col] = f2bf(oacc[mi][n][r] * linv[mi][r]);
      }
}

extern "C" void kernel_launch(void* const* d_in, const int* in_sizes, int n_in,
                              void* d_out, int out_size, void* d_ws, size_t ws_size,
                              hipStream_t stream) {
  const float* x  = (const float*)d_in[0];
  const float* cs = (const float*)d_in[1];
  const float* wq = (const float*)d_in[2];
  const float* wk = (const float*)d_in[3];
  const float* wv = (const float*)d_in[4];
  const float* wo = (const float*)d_in[5];
  float* out = (float*)d_out;

  char* ws = (char*)d_ws;
  unsigned short* xb   = (unsigned short*)(ws);               // 16 MB  x bf16
  unsigned short* wqt  = (unsigned short*)(ws + 16777216);    // 32 MB  wq^T } contiguous
  unsigned short* wkt  = (unsigned short*)(ws + 50331648);    // 8 MB   wk^T } B for fused
  unsigned short* wvt  = (unsigned short*)(ws + 58720256);    // 8 MB   wv^T } QKV gemm
  unsigned short* wot  = (unsigned short*)(ws + 67108864);    // 32 MB  wo^T
  unsigned short* QKVb = (unsigned short*)(ws + 100663296);   // 24 MB  [Q|K|V]
  unsigned short* Vtb  = (unsigned short*)(ws + 125829120);   // 4 MB   V^T
  unsigned short* Ob   = xb;  // alias: xb dead after QKV gemm

  convert_f32_bf16<<<8192, 256, 0, stream>>>(x, xb, 2097152);
  transpose_f32_bf16<<<dim3(64, 64), 256, 0, stream>>>(wq, wqt, 4096, 4096);
  transpose_f32_bf16<<<dim3(16, 64), 256, 0, stream>>>(wk, wkt, 4096, 1024);
  transpose_f32_bf16<<<dim3(16, 64), 256, 0, stream>>>(wv, wvt, 4096, 1024);
  transpose_f32_bf16<<<dim3(64, 64), 256, 0, stream>>>(wo, wot, 4096, 4096);

  // QKV: BM=256 x BN=192, grid 32x8 = 256 blocks (perfect fill, 1/CU)
  gemm_pipe<3, false><<<256, 512, 0, stream>>>(xb, wqt, QKVb, 2048, 6144, 4096);

  // Q scale folds softmax 1/sqrt(128) AND log2(e) for exp2-based softmax
  rope_kernel<<<4096, 256, 0, stream>>>(QKVb, cs, 32, 6144, 0, 0.12751743f);
  rope_kernel<<<1024, 256, 0, stream>>>(QKVb, cs, 8, 6144, 4096, 1.0f);

  v_transpose<<<dim3(64, 4, 8), 256, 0, stream>>>(QKVb, Vtb);

  flash_kernel<<<512, 256, 0, stream>>>(QKVb, Vtb, Ob);

  // O-proj: BM=256 x BN=128, grid 32x8 = 256 blocks (perfect fill)
  gemm_pipe<2, true><<<256, 512, 0, stream>>>(Ob, wot, out, 2048, 4096, 4096);
}

// Round 4
// 488.526 us; speedup vs baseline: 1.1369x; 1.1369x over previous
//
#include <hip/hip_runtime.h>
#include <hip/hip_bf16.h>
#include <cstdint>
#include <cstddef>

typedef __bf16 bf16x8 __attribute__((ext_vector_type(8)));
typedef float floatx4 __attribute__((ext_vector_type(4)));

#define MFMA(a, b, c) __builtin_amdgcn_mfma_f32_16x16x32_bf16((a), (b), (c), 0, 0, 0)
#define WAITVM(N) asm volatile("s_waitcnt vmcnt(" #N ")" ::: "memory")
#define WAITLGKM0() asm volatile("s_waitcnt lgkmcnt(0)" ::: "memory")
#define BARRIER() do { asm volatile("" ::: "memory"); __builtin_amdgcn_s_barrier(); asm volatile("" ::: "memory"); } while (0)
#define SCHEDBAR() __builtin_amdgcn_sched_barrier(0)

__device__ __forceinline__ unsigned short f2bf(float f) {
  unsigned u = __builtin_bit_cast(unsigned, f);
  u += 0x7fffu + ((u >> 16) & 1u);
  return (unsigned short)(u >> 16);
}
__device__ __forceinline__ float bf2f(unsigned short h) {
  unsigned u = ((unsigned)h) << 16;
  return __builtin_bit_cast(float, u);
}
__device__ __forceinline__ float fast_exp2(float x) {
#if __has_builtin(__builtin_amdgcn_exp2f)
  return __builtin_amdgcn_exp2f(x);
#else
  return exp2f(x);
#endif
}

// async 16B global -> LDS DMA. LDS dest = wave-uniform base + lane*16.
__device__ __forceinline__ void gl2lds16(const unsigned short* g, unsigned short* l) {
  __builtin_amdgcn_global_load_lds(
      (const __attribute__((address_space(1))) unsigned int*)g,
      (__attribute__((address_space(3))) unsigned int*)l, 16, 0, 0);
}

// ---------------- fp32 -> bf16 convert (x) ----------------
__global__ void convert_f32_bf16(const float* __restrict__ src,
                                 unsigned short* __restrict__ dst, int n4) {
  int i = blockIdx.x * 256 + threadIdx.x;
  if (i >= n4) return;
  float4 f = ((const float4*)src)[i];
  ushort4 o;
  o.x = f2bf(f.x); o.y = f2bf(f.y); o.z = f2bf(f.z); o.w = f2bf(f.w);
  ((ushort4*)dst)[i] = o;
}

// ---------------- fp32 (K x N) -> bf16 transposed (N x K), 64x64 tiles ----------------
__global__ void transpose_f32_bf16(const float* __restrict__ src,
                                   unsigned short* __restrict__ dst, int K, int N) {
  __shared__ float tile[64 * 65];
  int tn = blockIdx.x * 64, tk = blockIdx.y * 64;
  int r = threadIdx.x >> 4;          // 0..15
  int c4 = (threadIdx.x & 15) * 4;   // 0,4,..,60
#pragma unroll
  for (int i = 0; i < 4; i++) {
    float4 f = *(const float4*)&src[(size_t)(tk + r + 16 * i) * N + tn + c4];
    float* tr = &tile[(r + 16 * i) * 65 + c4];
    tr[0] = f.x; tr[1] = f.y; tr[2] = f.z; tr[3] = f.w;
  }
  __syncthreads();
#pragma unroll
  for (int i = 0; i < 4; i++) {
    ushort4 o;
    o.x = f2bf(tile[(c4 + 0) * 65 + r + 16 * i]);
    o.y = f2bf(tile[(c4 + 1) * 65 + r + 16 * i]);
    o.z = f2bf(tile[(c4 + 2) * 65 + r + 16 * i]);
    o.w = f2bf(tile[(c4 + 3) * 65 + r + 16 * i]);
    *(ushort4*)&dst[(size_t)(tn + r + 16 * i) * K + tk + c4] = o;
  }
}

// ---------------- phased-pipeline bf16 GEMM: C = A(MxK) * Bt(NxK)^T ----------------
// BM = MI*32, BN = NI*64, BK=64, 512 threads (8 waves 2x4), per-wave output
// (MI*16) x (NI*16). Double-buffered LDS, source-side XOR colgroup swizzle
// (validated SQ_LDS_BANK_CONFLICT=0), counted vmcnt (never 0 in steady state),
// setprio around MFMA clusters. R1-validated schedule (4.3 TF/CU): all fragment
// ds_reads issue in P0 and drain at P0's WAITLGKM0 BEFORE the barrier that
// precedes any staging -> tile T+2 stores into buf T&1 can never race tile T
// reads. vmcnt(NST) at last phase leaves T+2's NST loads in flight, forces
// T+1 landed before its P0 reads. Natural 2-D grid (x = bn fastest): FETCH
// measured ~90 MB (R0/R1); do NOT add manual XCD swizzle (R2: 205 MB).
template <int MI, int NI, bool F32OUT>
__global__ __launch_bounds__(512, 2) void gemm_pipe(
    const unsigned short* __restrict__ A,
    const unsigned short* __restrict__ Bt,
    void* __restrict__ C, int M, int N, int K) {
  constexpr int BM = MI * 32;
  constexpr int BN = NI * 64;
  constexpr int NCA = BM / 64;       // A 64-row chunks per tile (4 or 2)
  __shared__ alignas(16) unsigned short Al[2][BM * 64];
  __shared__ alignas(16) unsigned short Bl[2][BN * 64];
  const int tid = threadIdx.x;
  const int w = tid >> 6, L = tid & 63;
  const int lr = L & 15, lg = L >> 4, lr7 = lr & 7;
  const int bm = blockIdx.y * BM, bn = blockIdx.x * BN;
  const int wm = (w >> 2) * (MI * 16);
  const int wn = (w & 3) * (NI * 16);
  const int NT = K >> 6;

  // staging map: thread -> (row = tid>>3 within 64-row chunk, colgroup = tid&7)
  // LDS dest = chunk base + tid*16B; source colgroup XOR-swizzled by row&7.
  const int srow = tid >> 3, scg = tid & 7;
  const unsigned short* Ag = &A[(size_t)(bm + srow) * K + ((scg ^ (srow & 7)) * 8)];
  const unsigned short* Bg = &Bt[(size_t)(bn + srow) * K + ((scg ^ (srow & 7)) * 8)];
  unsigned short* AlT = &Al[0][0] + tid * 8;
  unsigned short* BlT = &Bl[0][0] + tid * 8;

  // prologue: stage K-tiles 0 and 1
#pragma unroll
  for (int t = 0; t < 2; ++t) {
#pragma unroll
    for (int c = 0; c < NCA; ++c)
      gl2lds16(Ag + (size_t)(c * 64) * K + t * 64, AlT + t * (BM * 64) + c * 4096);
#pragma unroll
    for (int c = 0; c < NI; ++c)
      gl2lds16(Bg + (size_t)(c * 64) * K + t * 64, BlT + t * (BN * 64) + c * 4096);
  }

  floatx4 acc[MI][NI] = {};

#define CLUSTER(MLO, KK)                                                    \
  do {                                                                      \
    __builtin_amdgcn_s_setprio(1);                                          \
    _Pragma("unroll") for (int mi = 0; mi < 4; ++mi)                        \
        _Pragma("unroll") for (int ni = 0; ni < NI; ++ni)                   \
            acc[(MLO) + mi][ni] =                                           \
        MFMA(af[(MLO) + mi][KK], bq[ni][KK], acc[(MLO) + mi][ni]);          \
    __builtin_amdgcn_s_setprio(0);                                          \
  } while (0)

  // NST = NCA + NI loads per tile in flight for tile T+2
  if constexpr (NCA + NI == 7) WAITVM(7); else WAITVM(6);  // tile0 landed
  BARRIER();

  for (int T = 0; T < NT; ++T) {
    const int buf = T & 1;
    const unsigned short* Ab = &Al[buf][0];
    const unsigned short* Bb = &Bl[buf][0];
    const bool st = (T + 2) < NT;
    const size_t kofs = (size_t)(T + 2) * 64;
    unsigned short* Ad = AlT + buf * (BM * 64);
    unsigned short* Bd = BlT + buf * (BN * 64);

    // ---- P0: ALL fragment reads, then first cluster ----
    bf16x8 af[MI][2], bq[NI][2];
#pragma unroll
    for (int mi = 0; mi < MI; ++mi) {
      af[mi][0] = *(const bf16x8*)&Ab[(wm + mi * 16 + lr) * 64 + ((lg ^ lr7) * 8)];
      af[mi][1] = *(const bf16x8*)&Ab[(wm + mi * 16 + lr) * 64 + (((4 + lg) ^ lr7) * 8)];
    }
#pragma unroll
    for (int ni = 0; ni < NI; ++ni) {
      bq[ni][0] = *(const bf16x8*)&Bb[(wn + ni * 16 + lr) * 64 + ((lg ^ lr7) * 8)];
      bq[ni][1] = *(const bf16x8*)&Bb[(wn + ni * 16 + lr) * 64 + (((4 + lg) ^ lr7) * 8)];
    }

    if constexpr (MI == 8) {
      CLUSTER(0, 0);
      WAITLGKM0();                     // ALL tile-T reads in registers
      BARRIER(); SCHEDBAR();
      // ---- P1 ----
      if (st) {
        gl2lds16(Ag + kofs, Ad);
        gl2lds16(Ag + (size_t)64 * K + kofs, Ad + 4096);
        gl2lds16(Ag + (size_t)128 * K + kofs, Ad + 2 * 4096);
      }
      CLUSTER(4, 0);
      BARRIER(); SCHEDBAR();
      // ---- P2 ----
      if (st) {
        gl2lds16(Ag + (size_t)192 * K + kofs, Ad + 3 * 4096);
        gl2lds16(Bg + kofs, Bd);
        if constexpr (NI >= 2) gl2lds16(Bg + (size_t)64 * K + kofs, Bd + 4096);
      }
      CLUSTER(0, 1);
      BARRIER(); SCHEDBAR();
      // ---- P3 ----
      if (st) {
#pragma unroll
        for (int c = 2; c < NI; ++c)
          gl2lds16(Bg + (size_t)(c * 64) * K + kofs, Bd + c * 4096);
      }
      CLUSTER(4, 1);
      if constexpr (NCA + NI == 7) { if (st) { WAITVM(7); } else if (T + 1 < NT) { WAITVM(0); } }
      else                         { if (st) { WAITVM(6); } else if (T + 1 < NT) { WAITVM(0); } }
      BARRIER(); SCHEDBAR();
    } else {
      CLUSTER(0, 0);
      WAITLGKM0();
      BARRIER(); SCHEDBAR();
      // ---- P1 ----
      if (st) {
#pragma unroll
        for (int c = 0; c < NCA; ++c)
          gl2lds16(Ag + (size_t)(c * 64) * K + kofs, Ad + c * 4096);
#pragma unroll
        for (int c = 0; c < NI; ++c)
          gl2lds16(Bg + (size_t)(c * 64) * K + kofs, Bd + c * 4096);
      }
      CLUSTER(0, 1);
      if constexpr (NCA + NI == 7) { if (st) { WAITVM(7); } else if (T + 1 < NT) { WAITVM(0); } }
      else                         { if (st) { WAITVM(6); } else if (T + 1 < NT) { WAITVM(0); } }
      BARRIER(); SCHEDBAR();
    }
  }
#undef CLUSTER

#pragma unroll
  for (int mi = 0; mi < MI; ++mi) {
#pragma unroll
    for (int ni = 0; ni < NI; ++ni) {
#pragma unroll
      for (int r = 0; r < 4; ++r) {
        size_t row = bm + wm + mi * 16 + lg * 4 + r;
        size_t col = bn + wn + ni * 16 + lr;
        float v = acc[mi][ni][r];
        if constexpr (F32OUT) ((float*)C)[row * N + col] = v;
        else ((unsigned short*)C)[row * N + col] = f2bf(v);
      }
    }
  }
}

// ---------------- RoPE in place on bf16 rows, vectorized x4 ----------------
__global__ void rope_kernel(unsigned short* __restrict__ X, const float* __restrict__ cs,
                            int H, int rowStride, int colOff, float scale) {
  int idx = blockIdx.x * 256 + threadIdx.x;
  int dg = idx & 15;            // 4-wide d group: d = dg*4..dg*4+3
  int h = (idx >> 4) % H;
  int s = idx / (16 * H);
  size_t base = (size_t)s * rowStride + colOff + (size_t)h * 128 + dg * 4;
  ushort4 xa = *(const ushort4*)&X[base];
  ushort4 xb = *(const ushort4*)&X[base + 64];
  float4 c = *(const float4*)&cs[s * 64 + dg * 4];
  float4 sn = *(const float4*)&cs[2048 * 64 + s * 64 + dg * 4];
  ushort4 oa, ob;
  {
    float x1 = bf2f(xa.x), x2 = bf2f(xb.x);
    oa.x = f2bf((x1 * c.x + x2 * sn.x) * scale);
    ob.x = f2bf((x2 * c.x - x1 * sn.x) * scale);
  }
  {
    float x1 = bf2f(xa.y), x2 = bf2f(xb.y);
    oa.y = f2bf((x1 * c.y + x2 * sn.y) * scale);
    ob.y = f2bf((x2 * c.y - x1 * sn.y) * scale);
  }
  {
    float x1 = bf2f(xa.z), x2 = bf2f(xb.z);
    oa.z = f2bf((x1 * c.z + x2 * sn.z) * scale);
    ob.z = f2bf((x2 * c.z - x1 * sn.z) * scale);
  }
  {
    float x1 = bf2f(xa.w), x2 = bf2f(xb.w);
    oa.w = f2bf((x1 * c.w + x2 * sn.w) * scale);
    ob.w = f2bf((x2 * c.w - x1 * sn.w) * scale);
  }
  *(ushort4*)&X[base] = oa;
  *(ushort4*)&X[base + 64] = ob;
}

// ---------------- V (cols 5120.. of QKV, stride 6144) -> Vt (8,128,2048) ----------------
__global__ void v_transpose(const unsigned short* __restrict__ QKV,
                            unsigned short* __restrict__ Vt) {
  __shared__ unsigned short tile[32][33];
  int h = blockIdx.z;
  int s0 = blockIdx.x * 32, d0 = blockIdx.y * 32;
  int c = threadIdx.x & 31, r0 = threadIdx.x >> 5;
#pragma unroll
  for (int i = 0; i < 32; i += 8)
    tile[r0 + i][c] = QKV[(size_t)(s0 + r0 + i) * 6144 + 5120 + h * 128 + d0 + c];
  __syncthreads();
#pragma unroll
  for (int i = 0; i < 32; i += 8)
    Vt[(size_t)(h * 128 + d0 + r0 + i) * 2048 + s0 + c] = tile[c][r0 + i];
}

// ---------------- causal flash attention (v2) ----------------
// Block = 2 heads (same KV group) x 64 q-rows; 4 waves: wave w -> head
// hq = hk*4 + hp*2 + (w&1), q-rows [qb*64 + (w>>1)*32, +32) (2 row-tiles).
// K/V tile (64 positions) staged once per block via global_load_lds with
// source-side XOR colgroup swizzle (conflict-free ds_read_b128, zero staging
// VALU). 2x MFMA per staged byte vs v1. Fixed-max exp2 softmax (r3-validated).
__global__ __launch_bounds__(256) void flash_kernel(
    const unsigned short* __restrict__ QKV,  // (2048, 6144) roped; Q pre-scaled
    const unsigned short* __restrict__ Vt,   // (8, 128, 2048)
    unsigned short* __restrict__ O) {        // (2048, 4096)
  constexpr int PSTR = 72;
  __shared__ alignas(16) unsigned short Klds[64 * 128];   // 16 KB, swizzled cg16
  __shared__ alignas(16) unsigned short Vlds[128 * 64];   // 16 KB, swizzled cg8
  __shared__ alignas(16) unsigned short Plds[4 * 32 * PSTR];  // 18 KB wave-private
  const int tid = threadIdx.x, w = tid >> 6, L = tid & 63;
  const int lr = L & 15, lg = L >> 4;
  const int bid = blockIdx.x;
  const int hk = bid & 7;
  const int hp = (bid >> 3) & 1;
  const int qb = 31 - (bid >> 4);          // heavy blocks dispatch first
  const int hq = hk * 4 + hp * 2 + (w & 1);
  const int qr0 = qb * 64 + (w >> 1) * 32; // wave's 32 q-rows
  const unsigned short* Kg = QKV + 4096;

  // K staging (per thread, 4 issues/tile): row=flat>>4, lcg=flat&15,
  // source cg = lcg ^ (row&15)  -> LDS[row][lcg] holds logical cg lcg^(row&15)
  const int k_row = tid >> 4, k_lcg = tid & 15;
  const unsigned short* KgT = &Kg[(size_t)k_row * 6144 + hk * 128 + ((k_lcg ^ (k_row & 15)) * 8)];
  unsigned short* KlT = &Klds[k_row * 128 + k_lcg * 8];
  // V staging: row=flat>>3 (dh), lcg=flat&7, source cg = lcg ^ (row&7)
  const int v_row = tid >> 3, v_lcg = tid & 7;
  const unsigned short* VgT = &Vt[(size_t)(hk * 128 + v_row) * 2048 + ((v_lcg ^ (v_row & 7)) * 8)];
  unsigned short* VlT = &Vlds[v_row * 64 + v_lcg * 8];

  bf16x8 qf[2][4];
#pragma unroll
  for (int mi = 0; mi < 2; mi++)
#pragma unroll
    for (int c = 0; c < 4; c++)
      qf[mi][c] = *(const bf16x8*)&QKV[(size_t)(qr0 + mi * 16 + lr) * 6144 + hq * 128 + c * 32 + lg * 8];

  floatx4 oacc[2][8] = {};
  float l_lane[2][4] = {};
  unsigned short* pw = &Plds[w * 32 * PSTR];

  for (int t = 0; t <= qb; t++) {
    const int kv0 = t * 64;
    __syncthreads();  // previous tile's K/V reads done before restaging
#pragma unroll
    for (int i = 0; i < 4; i++) {
      gl2lds16(KgT + (size_t)(kv0 + i * 16) * 6144, KlT + i * 16 * 128);
      gl2lds16(VgT + kv0 + (size_t)(i * 32) * 2048, VlT + i * 32 * 64);
    }
    __syncthreads();

#pragma unroll
    for (int nt = 0; nt < 4; nt++) {
      bf16x8 kf[4];
#pragma unroll
      for (int c = 0; c < 4; c++)
        kf[c] = *(const bf16x8*)&Klds[(nt * 16 + lr) * 128 + (((c * 4 + lg) ^ lr) * 8)];
      floatx4 sc[2];
#pragma unroll
      for (int mi = 0; mi < 2; mi++) {
        floatx4 a = {};
#pragma unroll
        for (int c = 0; c < 4; c++) a = MFMA(qf[mi][c], kf[c], a);
        sc[mi] = a;
      }
      if (t == qb) {  // diagonal tile: causal mask
#pragma unroll
        for (int mi = 0; mi < 2; mi++)
#pragma unroll
          for (int r = 0; r < 4; r++)
            if (kv0 + nt * 16 + lr > qr0 + mi * 16 + lg * 4 + r) sc[mi][r] = -3e38f;
      }
#pragma unroll
      for (int mi = 0; mi < 2; mi++)
#pragma unroll
        for (int r = 0; r < 4; r++) {
          float p = fast_exp2(sc[mi][r]);
          l_lane[mi][r] += p;
          pw[(mi * 16 + lg * 4 + r) * PSTR + nt * 16 + lr] = f2bf(p);
        }
    }

    // P (wave-private) -> A-fragments; lgkmcnt orders ds_write->ds_read
    bf16x8 pf[2][2];
#pragma unroll
    for (int mi = 0; mi < 2; mi++)
#pragma unroll
      for (int c = 0; c < 2; c++)
        pf[mi][c] = *(const bf16x8*)&pw[(mi * 16 + lr) * PSTR + c * 32 + lg * 8];

#pragma unroll
    for (int n = 0; n < 8; n++) {
#pragma unroll
      for (int c = 0; c < 2; c++) {
        bf16x8 vf = *(const bf16x8*)&Vlds[(n * 16 + lr) * 64 + (((c * 4 + lg) ^ (lr & 7)) * 8)];
#pragma unroll
        for (int mi = 0; mi < 2; mi++) oacc[mi][n] = MFMA(pf[mi][c], vf, oacc[mi][n]);
      }
    }
  }

  // row-sum across the 16 lr lanes (masks 1..8 stay within lr group)
  float linv[2][4];
#pragma unroll
  for (int mi = 0; mi < 2; mi++)
#pragma unroll
    for (int r = 0; r < 4; r++) {
      float l = l_lane[mi][r];
      l += __shfl_xor(l, 1);
      l += __shfl_xor(l, 2);
      l += __shfl_xor(l, 4);
      l += __shfl_xor(l, 8);
      linv[mi][r] = 1.0f / l;
    }

#pragma unroll
  for (int mi = 0; mi < 2; mi++)
#pragma unroll
    for (int n = 0; n < 8; n++)
#pragma unroll
      for (int r = 0; r < 4; r++) {
        size_t row = qr0 + mi * 16 + lg * 4 + r;
        size_t col = (size_t)hq * 128 + n * 16 + lr;
        O[row * 4096 + col] = f2bf(oacc[mi][n][r] * linv[mi][r]);
      }
}

extern "C" void kernel_launch(void* const* d_in, const int* in_sizes, int n_in,
                              void* d_out, int out_size, void* d_ws, size_t ws_size,
                              hipStream_t stream) {
  const float* x  = (const float*)d_in[0];
  const float* cs = (const float*)d_in[1];
  const float* wq = (const float*)d_in[2];
  const float* wk = (const float*)d_in[3];
  const float* wv = (const float*)d_in[4];
  const float* wo = (const float*)d_in[5];
  float* out = (float*)d_out;

  char* ws = (char*)d_ws;
  unsigned short* xb   = (unsigned short*)(ws);               // 16 MB  x bf16
  unsigned short* wqt  = (unsigned short*)(ws + 16777216);    // 32 MB  wq^T } contiguous
  unsigned short* wkt  = (unsigned short*)(ws + 50331648);    // 8 MB   wk^T } B for fused
  unsigned short* wvt  = (unsigned short*)(ws + 58720256);    // 8 MB   wv^T } QKV gemm
  unsigned short* wot  = (unsigned short*)(ws + 67108864);    // 32 MB  wo^T
  unsigned short* QKVb = (unsigned short*)(ws + 100663296);   // 24 MB  [Q|K|V]
  unsigned short* Vtb  = (unsigned short*)(ws + 125829120);   // 4 MB   V^T
  unsigned short* Ob   = xb;  // alias: xb dead after QKV gemm

  convert_f32_bf16<<<8192, 256, 0, stream>>>(x, xb, 2097152);
  transpose_f32_bf16<<<dim3(64, 64), 256, 0, stream>>>(wq, wqt, 4096, 4096);
  transpose_f32_bf16<<<dim3(16, 64), 256, 0, stream>>>(wk, wkt, 4096, 1024);
  transpose_f32_bf16<<<dim3(16, 64), 256, 0, stream>>>(wv, wvt, 4096, 1024);
  transpose_f32_bf16<<<dim3(64, 64), 256, 0, stream>>>(wo, wot, 4096, 4096);

  // QKV: BM=256 x BN=192, grid (32,8) = 256 blocks, natural 2-D mapping
  gemm_pipe<8, 3, false><<<dim3(32, 8), 512, 0, stream>>>(xb, wqt, QKVb, 2048, 6144, 4096);

  // Q scale folds softmax 1/sqrt(128) AND log2(e) for exp2-based softmax
  rope_kernel<<<4096, 256, 0, stream>>>(QKVb, cs, 32, 6144, 0, 0.12751743f);
  rope_kernel<<<1024, 256, 0, stream>>>(QKVb, cs, 8, 6144, 4096, 1.0f);

  v_transpose<<<dim3(64, 4, 8), 256, 0, stream>>>(QKVb, Vtb);

  flash_kernel<<<512, 256, 0, stream>>>(QKVb, Vtb, Ob);

  // O-proj: BM=128 x BN=256, grid (16,16) = 256 blocks (R1-measured config)
  gemm_pipe<4, 4, true><<<dim3(16, 16), 512, 0, stream>>>(Ob, wot, out, 2048, 4096, 4096);
}